// Round 6
// baseline (434.241 us; speedup 1.0000x reference)
//
#include <hip/hip_runtime.h>
#include <hip/hip_bf16.h>
#include <math.h>

// ---------------------------------------------------------------------------
// GCN forward: out = log_softmax( A@( relu(A@(x@W1)+b1) @ W2 ) + b2 )
// Round 6: same as R5 (spmm2 1-row/wave 3-edges/instr; spmm1 2-edges/gather)
// with the nontemporal_store compile fix (pack uint2 -> unsigned long long).
// ---------------------------------------------------------------------------

#define GCN_NFEAT 256
#define GCN_NHID  128
#define GCN_NCLASS 40

typedef __bf16 bf16_t;
typedef bf16_t bf16x8 __attribute__((ext_vector_type(8)));
typedef float  f32x4  __attribute__((ext_vector_type(4)));

static __device__ __forceinline__ unsigned short f2b(float f) {
    bf16_t b = (bf16_t)f;
    return *(unsigned short*)&b;
}
static __device__ __forceinline__ float blo(unsigned int u) {
    return __uint_as_float(u << 16);
}
static __device__ __forceinline__ float bhi(unsigned int u) {
    return __uint_as_float(u & 0xffff0000u);
}

// ---- row_ptr[r] = lower_bound(adj_row, r), r in [0, N] ---------------------
__global__ __launch_bounds__(256) void k_row_ptr(
    const int* __restrict__ row, int* __restrict__ row_ptr, int n_rows, int n_edges)
{
    int r = blockIdx.x * blockDim.x + threadIdx.x;
    if (r > n_rows) return;
    int lo = 0, hi = n_edges;
    while (lo < hi) {
        int mid = (lo + hi) >> 1;
        if (row[mid] < r) lo = mid + 1; else hi = mid;
    }
    row_ptr[r] = lo;
}

// ---- prep: W1t_bf16[128][256] = bf16(W1[k][c]) transposed ------------------
__global__ __launch_bounds__(256) void k_prep_w1t(
    const float* __restrict__ w1, bf16_t* __restrict__ w1t)
{
    int idx = blockIdx.x * 256 + threadIdx.x;           // 128*256 total
    int c = idx & 127;
    int k = idx >> 7;
    w1t[(size_t)c * GCN_NFEAT + k] = (bf16_t)w1[(size_t)k * GCN_NHID + c];
}

// ---- prep: W2t_bf16[48][128], cols 40..47 zero -----------------------------
__global__ __launch_bounds__(256) void k_prep_w2t(
    const float* __restrict__ w2, bf16_t* __restrict__ w2t)
{
    int idx = blockIdx.x * 256 + threadIdx.x;           // 48*128 = 6144 total
    if (idx >= 48 * GCN_NHID) return;
    int c = idx / GCN_NHID;
    int k = idx - c * GCN_NHID;
    float v = (c < GCN_NCLASS) ? w2[(size_t)k * GCN_NCLASS + c] : 0.f;
    w2t[idx] = (bf16_t)v;
}

// ---- GEMM1 (MFMA): sup1_bf16[N,128] = bf16( x[N,256] @ W1 ) ----------------
__global__ __launch_bounds__(256) void k_gemm1(
    const float* __restrict__ x, const bf16_t* __restrict__ w1t,
    bf16_t* __restrict__ out, int nrows)
{
    __shared__ __align__(16) bf16_t As[128][72];   // [row][k]
    __shared__ __align__(16) bf16_t Bs[128][72];   // [col][k]

    const int tid  = threadIdx.x;
    const int wave = tid >> 6, lane = tid & 63;
    const int wm = wave >> 1, wn = wave & 1;
    const int lm = lane & 15, quad = lane >> 4;
    const int r0 = blockIdx.x * 128;

    f32x4 acc[4][4] = {};

    for (int k0 = 0; k0 < GCN_NFEAT; k0 += 64) {
        {
            const int row = tid >> 1, half = tid & 1;
            const int gr = r0 + row;
            union { bf16_t b[32]; uint4 q[4]; } t;
            if (gr < nrows) {
                const float* p = x + (size_t)gr * GCN_NFEAT + k0 + half * 32;
#pragma unroll
                for (int i = 0; i < 8; i++) {
                    float4 v = ((const float4*)p)[i];
                    t.b[i*4+0] = (bf16_t)v.x; t.b[i*4+1] = (bf16_t)v.y;
                    t.b[i*4+2] = (bf16_t)v.z; t.b[i*4+3] = (bf16_t)v.w;
                }
            } else {
#pragma unroll
                for (int i = 0; i < 4; i++) t.q[i] = make_uint4(0,0,0,0);
            }
            uint4* dst = (uint4*)&As[row][half * 32];
#pragma unroll
            for (int i = 0; i < 4; i++) dst[i] = t.q[i];
        }
        {
            const int colc = tid >> 1, half = tid & 1;
            const uint4* src = (const uint4*)(w1t + (size_t)colc * GCN_NFEAT + k0 + half * 32);
            uint4* dst = (uint4*)&Bs[colc][half * 32];
#pragma unroll
            for (int i = 0; i < 4; i++) dst[i] = src[i];
        }
        __syncthreads();

#pragma unroll
        for (int ks = 0; ks < 2; ks++) {
            bf16x8 af[4], bfr[4];
#pragma unroll
            for (int i = 0; i < 4; i++)
                af[i] = *(const bf16x8*)&As[wm*64 + i*16 + lm][ks*32 + quad*8];
#pragma unroll
            for (int j = 0; j < 4; j++)
                bfr[j] = *(const bf16x8*)&Bs[wn*64 + j*16 + lm][ks*32 + quad*8];
#pragma unroll
            for (int i = 0; i < 4; i++)
#pragma unroll
                for (int j = 0; j < 4; j++)
                    acc[i][j] = __builtin_amdgcn_mfma_f32_16x16x32_bf16(
                        af[i], bfr[j], acc[i][j], 0, 0, 0);
        }
        __syncthreads();
    }

#pragma unroll
    for (int i = 0; i < 4; i++) {
#pragma unroll
        for (int reg = 0; reg < 4; reg++) {
            const int gr = r0 + wm*64 + i*16 + quad*4 + reg;
            if (gr < nrows) {
#pragma unroll
                for (int j = 0; j < 4; j++) {
                    const int gc = wn*64 + j*16 + lm;
                    out[(size_t)gr * GCN_NHID + gc] = (bf16_t)acc[i][j][reg];
                }
            }
        }
    }
}

// ---- spmm1: h_bf16[r,:] = relu( sum_e val[e]*sup1[col[e],:] + b1 ) ---------
// wave per row; 2 edges per gather instr (eg=lane>>5 owns edge parity, 32
// lanes x 8B = 256B per edge); 16-edge chunks, col/val loaded once by lanes
// 0-15 and shfl-broadcast; cross-half xor-reduce at the end.
__global__ __launch_bounds__(256) void k_spmm1(
    const int* __restrict__ row_ptr, const int* __restrict__ col,
    const float* __restrict__ val, const unsigned long long* __restrict__ sup,
    const float* __restrict__ b1, unsigned long long* __restrict__ h, int nrows)
{
    const int wid  = (blockIdx.x * blockDim.x + threadIdx.x) >> 6;
    const int lane = threadIdx.x & 63;
    if (wid >= nrows) return;
    const int e0 = row_ptr[wid];
    const int e1 = row_ptr[wid + 1];
    const int eg = lane >> 5;        // 0: even edges, 1: odd edges
    const int li = lane & 31;        // owns 8B chunk li (dims 4li..4li+3)

    float a0 = 0.f, a1 = 0.f, a2 = 0.f, a3 = 0.f;

    int e = e0;
    for (; e + 16 <= e1; e += 16) {
        const int   cv = __builtin_nontemporal_load(&col[e + (lane & 15)]);
        const float vv = __builtin_nontemporal_load(&val[e + (lane & 15)]);
#pragma unroll
        for (int s = 0; s < 8; s++) {
            const int   cj = __shfl(cv, 2 * s + eg, 64);
            const float vj = __shfl(vv, 2 * s + eg, 64);
            const unsigned long long u = sup[((unsigned)cj << 5) + li];
            const unsigned int ux = (unsigned int)u;
            const unsigned int uy = (unsigned int)(u >> 32);
            a0 = fmaf(vj, blo(ux), a0); a1 = fmaf(vj, bhi(ux), a1);
            a2 = fmaf(vj, blo(uy), a2); a3 = fmaf(vj, bhi(uy), a3);
        }
    }
    // tail pairs (both halves used)
    for (; e + 2 <= e1; e += 2) {
        const int   c = col[e + eg];
        const float v = val[e + eg];
        const unsigned long long u = sup[((unsigned)c << 5) + li];
        const unsigned int ux = (unsigned int)u;
        const unsigned int uy = (unsigned int)(u >> 32);
        a0 = fmaf(v, blo(ux), a0); a1 = fmaf(v, bhi(ux), a1);
        a2 = fmaf(v, blo(uy), a2); a3 = fmaf(v, bhi(uy), a3);
    }
    // final odd edge (eg==0 half only)
    if (e < e1) {
        const int   c = col[e];
        const float v = val[e];
        if (eg == 0) {
            const unsigned long long u = sup[((unsigned)c << 5) + li];
            const unsigned int ux = (unsigned int)u;
            const unsigned int uy = (unsigned int)(u >> 32);
            a0 = fmaf(v, blo(ux), a0); a1 = fmaf(v, bhi(ux), a1);
            a2 = fmaf(v, blo(uy), a2); a3 = fmaf(v, bhi(uy), a3);
        }
    }

    // combine the two edge-parity halves
    a0 += __shfl_xor(a0, 32, 64);
    a1 += __shfl_xor(a1, 32, 64);
    a2 += __shfl_xor(a2, 32, 64);
    a3 += __shfl_xor(a3, 32, 64);

    if (eg == 0) {
        const float4 bb = *(const float4*)(b1 + li * 4);
        const float o0 = fmaxf(a0 + bb.x, 0.f);
        const float o1 = fmaxf(a1 + bb.y, 0.f);
        const float o2 = fmaxf(a2 + bb.z, 0.f);
        const float o3 = fmaxf(a3 + bb.w, 0.f);
        const unsigned long long pk =
            (unsigned long long)((unsigned int)f2b(o0) | ((unsigned int)f2b(o1) << 16)) |
            ((unsigned long long)((unsigned int)f2b(o2) | ((unsigned int)f2b(o3) << 16)) << 32);
        __builtin_nontemporal_store(pk, &h[((unsigned)wid << 5) + li]);
    }
}

// ---- GEMM2 (MFMA): sup2_bf16[N,40] = bf16( h[N,128] @ W2 ) -----------------
__global__ __launch_bounds__(256) void k_gemm2(
    const bf16_t* __restrict__ h, const bf16_t* __restrict__ w2t,
    bf16_t* __restrict__ out, int nrows)
{
    __shared__ __align__(16) bf16_t As[128][136];  // [row][k]
    __shared__ __align__(16) bf16_t Bs[48][136];   // [col][k]

    const int tid  = threadIdx.x;
    const int wave = tid >> 6, lane = tid & 63;
    const int lm = lane & 15, quad = lane >> 4;
    const int r0 = blockIdx.x * 128;

    {
        const int row = tid >> 1, half = tid & 1;
        const int gr = r0 + row;
        uint4* dst = (uint4*)&As[row][half * 64];
        if (gr < nrows) {
            const uint4* src = (const uint4*)(h + (size_t)gr * GCN_NHID + half * 64);
#pragma unroll
            for (int i = 0; i < 8; i++) dst[i] = src[i];
        } else {
#pragma unroll
            for (int i = 0; i < 8; i++) dst[i] = make_uint4(0,0,0,0);
        }
    }
    for (int idx = tid; idx < 48 * 16; idx += 256) {
        const int c = idx >> 4, seg = idx & 15;
        ((uint4*)&Bs[c][0])[seg] = ((const uint4*)(w2t + (size_t)c * GCN_NHID))[seg];
    }
    __syncthreads();

    f32x4 acc[2][3] = {};
#pragma unroll
    for (int ks = 0; ks < 4; ks++) {
        bf16x8 af[2], bfr[3];
#pragma unroll
        for (int i = 0; i < 2; i++)
            af[i] = *(const bf16x8*)&As[wave*32 + i*16 + lm][ks*32 + quad*8];
#pragma unroll
        for (int j = 0; j < 3; j++)
            bfr[j] = *(const bf16x8*)&Bs[j*16 + lm][ks*32 + quad*8];
#pragma unroll
        for (int i = 0; i < 2; i++)
#pragma unroll
            for (int j = 0; j < 3; j++)
                acc[i][j] = __builtin_amdgcn_mfma_f32_16x16x32_bf16(
                    af[i], bfr[j], acc[i][j], 0, 0, 0);
    }

#pragma unroll
    for (int i = 0; i < 2; i++) {
#pragma unroll
        for (int reg = 0; reg < 4; reg++) {
            const int gr = r0 + wave*32 + i*16 + quad*4 + reg;
            if (gr < nrows) {
#pragma unroll
                for (int j = 0; j < 3; j++) {
                    const int gc = j*16 + lm;
                    if (gc < GCN_NCLASS)
                        out[(size_t)gr * GCN_NCLASS + gc] = (bf16_t)acc[i][j][reg];
                }
            }
        }
    }
}

// ---- spmm2 + bias + log_softmax -> out[N,40] fp32 --------------------------
// ONE row per wave; 3 groups x 20 lanes, each gather instr serves 3 edges
// (group g takes edges e+s*3+g). 24-edge chunks with shfl broadcast. Lanes
// 60-63 mirror group 2 (results discarded). Cross-group shuffle reduce, then
// 20-lane softmax.
__global__ __launch_bounds__(256) void k_spmm2_lsm(
    const int* __restrict__ row_ptr, const int* __restrict__ col,
    const float* __restrict__ val, const unsigned int* __restrict__ sup2,
    const float* __restrict__ b2, float* __restrict__ out, int nrows)
{
    const int wid  = (blockIdx.x * blockDim.x + threadIdx.x) >> 6;
    const int lane = threadIdx.x & 63;
    if (wid >= nrows) return;
    int g = lane / 20;                     // 0..3
    const int li = lane - g * 20;          // 0..19 (lanes 60-63 -> 0..3)
    if (g > 2) g = 2;                      // lanes 60-63 mirror group 2

    const int e0 = row_ptr[wid];
    const int e1 = row_ptr[wid + 1];

    float ax = 0.f, ay = 0.f;
    int e = e0;
    for (; e + 24 <= e1; e += 24) {
        const int   idx = (lane < 24) ? lane : 0;
        const int   cv = __builtin_nontemporal_load(&col[e + idx]);
        const float vv = __builtin_nontemporal_load(&val[e + idx]);
#pragma unroll
        for (int s = 0; s < 8; s++) {
            const int   cj = __shfl(cv, s * 3 + g, 64);
            const float vj = __shfl(vv, s * 3 + g, 64);
            const unsigned int u = sup2[(unsigned)cj * 20 + li];
            ax = fmaf(vj, blo(u), ax);
            ay = fmaf(vj, bhi(u), ay);
        }
    }
    // tail: group g takes edges e+g, e+g+3, ...
    for (int et = e + g; et < e1; et += 3) {
        const int   c = col[et];
        const float v = val[et];
        const unsigned int u = sup2[(unsigned)c * 20 + li];
        ax = fmaf(v, blo(u), ax);
        ay = fmaf(v, bhi(u), ay);
    }

    // combine 3 groups: lane li(0-19) += lanes li+20, li+40
    {
        const float tx20 = __shfl_down(ax, 20, 64);
        const float tx40 = __shfl_down(ax, 40, 64);
        const float ty20 = __shfl_down(ay, 20, 64);
        const float ty40 = __shfl_down(ay, 40, 64);
        ax = ax + tx20 + tx40;
        ay = ay + ty20 + ty40;
    }

    const bool owner = (lane < 20);
    float l0 = -INFINITY, l1 = -INFINITY;
    if (owner) {
        const float2 bb = *(const float2*)(b2 + li * 2);
        l0 = ax + bb.x;
        l1 = ay + bb.y;
    }

    // 20-lane guarded reductions (lanes 0-19)
    float m = fmaxf(l0, l1);
#pragma unroll
    for (int off = 16; off >= 1; off >>= 1) {
        const float t = __shfl_down(m, off, 64);
        if (owner && li + off < 20) m = fmaxf(m, t);
    }
    m = __shfl(m, 0, 64);

    float s = owner ? (__expf(l0 - m) + __expf(l1 - m)) : 0.f;
#pragma unroll
    for (int off = 16; off >= 1; off >>= 1) {
        const float t = __shfl_down(s, off, 64);
        if (owner && li + off < 20) s += t;
    }
    s = __shfl(s, 0, 64);

    if (owner) {
        const float lse = m + __logf(s);
        float2 o = make_float2(l0 - lse, l1 - lse);
        *(float2*)(out + (size_t)wid * GCN_NCLASS + li * 2) = o;
    }
}

// ---------------------------------------------------------------------------
extern "C" void kernel_launch(void* const* d_in, const int* in_sizes, int n_in,
                              void* d_out, int out_size, void* d_ws, size_t ws_size,
                              hipStream_t stream)
{
    const float* x       = (const float*)d_in[0];
    const int*   adj_row = (const int*)  d_in[1];
    const int*   adj_col = (const int*)  d_in[2];
    const float* adj_val = (const float*)d_in[3];
    // d_in[4] = i (unused)
    const float* W1 = (const float*)d_in[5];
    const float* b1 = (const float*)d_in[6];
    const float* W2 = (const float*)d_in[7];
    const float* b2 = (const float*)d_in[8];
    float* out = (float*)d_out;

    const int N = in_sizes[0] / GCN_NFEAT;   // 100000
    const int E = in_sizes[1];               // 3200000

    // workspace layout (1 KiB aligned chunks)
    char* ws = (char*)d_ws;
    size_t off = 0;
    int* row_ptr = (int*)(ws + off);
    off += (((size_t)(N + 1) * sizeof(int)) + 1023) & ~(size_t)1023;
    bf16_t* w1t = (bf16_t*)(ws + off);                 // 128*256 bf16
    off += ((size_t)GCN_NHID * GCN_NFEAT * 2 + 1023) & ~(size_t)1023;
    bf16_t* w2t = (bf16_t*)(ws + off);                 // 48*128 bf16
    off += ((size_t)48 * GCN_NHID * 2 + 1023) & ~(size_t)1023;
    bf16_t* sup1 = (bf16_t*)(ws + off);                // N*128 bf16
    off += ((size_t)N * GCN_NHID * 2 + 1023) & ~(size_t)1023;
    bf16_t* h = (bf16_t*)(ws + off);                   // N*128 bf16
    bf16_t* sup2 = sup1;                               // reuse sup1 (N*40 bf16)

    k_row_ptr<<<(N + 1 + 255) / 256, 256, 0, stream>>>(adj_row, row_ptr, N, E);
    k_prep_w1t<<<GCN_NHID * GCN_NFEAT / 256, 256, 0, stream>>>(W1, w1t);
    k_prep_w2t<<<(48 * GCN_NHID + 255) / 256, 256, 0, stream>>>(W2, w2t);
    k_gemm1<<<(N + 127) / 128, 256, 0, stream>>>(x, w1t, sup1, N);
    k_spmm1<<<(N + 3) / 4, 256, 0, stream>>>(row_ptr, adj_col, adj_val,
                                             (const unsigned long long*)sup1, b1,
                                             (unsigned long long*)h, N);
    k_gemm2<<<(N + 127) / 128, 256, 0, stream>>>(h, w2t, sup2, N);
    k_spmm2_lsm<<<(N + 3) / 4, 256, 0, stream>>>(row_ptr, adj_col, adj_val,
                                                 (const unsigned int*)sup2, b2, out, N);
}